// Round 21
// baseline (164.538 us; speedup 1.0000x reference)
//
#include <hip/hip_runtime.h>
#include <hip/hip_fp16.h>

typedef _Float16 f16;
typedef __attribute__((ext_vector_type(8))) _Float16 f16x8;
typedef __attribute__((ext_vector_type(4))) _Float16 f16x4;
typedef __attribute__((ext_vector_type(2))) _Float16 f16x2;
typedef __attribute__((ext_vector_type(4))) float f32x4;

#define MFMA16(a, b, c) __builtin_amdgcn_mfma_f32_16x16x32_f16((a), (b), (c), 0, 0, 0)

// direct global->LDS DMA, 16B per lane (dest = wave-uniform base + lane*16)
#define GL16(SRC, DST)                                                        \
  __builtin_amdgcn_global_load_lds(                                           \
      (const __attribute__((address_space(1))) unsigned int*)(SRC),           \
      (__attribute__((address_space(3))) unsigned int*)(DST), 16, 0, 0)

// ---------------- workspace layout (bytes) ----------------
#define OFF_WK   0u              // w_k folded f16 [256][256]
#define OFF_WS   131072u         // w_s folded f16 [256][256]
#define OFF_WH1  262144u         // w_h1 folded f16 [256][256]
#define OFF_W2P  393216u         // w_h2 padded f16 [32][256]
#define OFF_SH   409600u         // shifts f32 [3][256]
#define OFF_S    412672u         // s feat f16 [123008][256]
#define OFF_KF   63392768u       // k feat f16 [6272][256]

// ---------------- weight prep ----------------
__global__ __launch_bounds__(256) void prep_weights(
    const float* __restrict__ wk, const float* __restrict__ gk, const float* __restrict__ bk,
    const float* __restrict__ mk, const float* __restrict__ vk,
    const float* __restrict__ wsr, const float* __restrict__ gs, const float* __restrict__ bs,
    const float* __restrict__ ms, const float* __restrict__ vs,
    const float* __restrict__ wh1, const float* __restrict__ gh, const float* __restrict__ bh,
    const float* __restrict__ mh, const float* __restrict__ vh,
    const float* __restrict__ wh2,
    f16* __restrict__ wk16, f16* __restrict__ ws16, f16* __restrict__ wh116,
    f16* __restrict__ w2p, float* __restrict__ shifts) {
  int o = blockIdx.x;
  int t = threadIdx.x;
  float sck = gk[o] * rsqrtf(vk[o] + 1e-5f);
  float scs = gs[o] * rsqrtf(vs[o] + 1e-5f);
  float sch = gh[o] * rsqrtf(vh[o] + 1e-5f);
  int idx = o * 256 + t;
  wk16[idx]  = (f16)(wk[idx] * sck);
  ws16[idx]  = (f16)(wsr[idx] * scs);
  wh116[idx] = (f16)(wh1[idx] * sch);
  if (o < 32) w2p[idx] = (o < 20) ? (f16)wh2[idx] : (f16)0;
  if (t == 0) {
    shifts[o]       = bk[o] - mk[o] * sck;
    shifts[256 + o] = bs[o] - ms[o] * scs;
    shifts[512 + o] = bh[o] - mh[o] * sch;
  }
}

// π row permutation for LDS B-tile (conv49)
__device__ __forceinline__ int pi_row(int q, int r) {  // n = 4q + r (q in 0..15)
  return (q ^ (r << 2)) + (r << 4);
}

// ---------------- conv961: global_load_lds, 3-buffer / 2-tiles-ahead pipeline -------
// Tile 128px x 256o, 8 waves. LDS: 3 x fp32 [32c][128px] linear buffers (48 KB).
// iter ci: issue DMA tile ci+2 -> buf[(ci+2)%3] (safe: last read iter ci-1, behind
// that iter's end-barrier) -> vmcnt(4) (tiles ci+1,ci+2 in flight; tile ci complete)
// -> s_barrier (block-wide completeness) -> frag reads + 16 MFMA -> end s_barrier.
__global__ __launch_bounds__(512) void conv_gl(
    const float* __restrict__ X, const f16* __restrict__ W,
    const float* __restrict__ shift, f16* __restrict__ out) {
  const int C = 256, P = 961;
  int b = blockIdx.x >> 3;
  int ti = blockIdx.x & 7;
  int n0 = ti * 128; if (n0 > P - 128) n0 = P - 128;   // tail overlap: dup identical writes
  int t = threadIdx.x;
  int w = t >> 6, lane = t & 63;
  int fm = lane & 15, kg = lane >> 4;
  int wo = (w & 3) * 64;          // o-base (4 groups)
  int wpx = (w >> 2) * 64;        // px-half

  __shared__ float Bs[3][32 * 128];   // [buf][c][px] fp32, 16 KB each

  // staging: wave w owns rows 4w..4w+3; instr j covers rows {4w+2j, 4w+2j+1}
  const float* s_src0 = X + ((size_t)b * C + 4 * w + (lane >> 5)) * P + n0 + (lane & 31) * 4;

  const f16* wp = W + (size_t)(wo + fm) * C + kg * 8;

  // prologue: tiles 0 and 1
  GL16(s_src0,              &Bs[0][(4 * w) * 128]);
  GL16(s_src0 + 2 * P,      &Bs[0][(4 * w + 2) * 128]);
  GL16(s_src0 + 32 * P,     &Bs[1][(4 * w) * 128]);
  GL16(s_src0 + 34 * P,     &Bs[1][(4 * w + 2) * 128]);

  f32x4 acc[4][4] = {};
#pragma unroll
  for (int ci = 0; ci < 8; ++ci) {
    float* buf = Bs[ci % 3];
    if (ci < 6) {
      const float* s = s_src0 + (size_t)(ci + 2) * 32 * P;
      float* d = Bs[(ci + 2) % 3];
      GL16(s,         &d[(4 * w) * 128]);
      GL16(s + 2 * P, &d[(4 * w + 2) * 128]);
      asm volatile("s_waitcnt vmcnt(4)" ::: "memory");   // tile ci done; ci+1, ci+2 in flight
    } else if (ci == 6) {
      asm volatile("s_waitcnt vmcnt(2)" ::: "memory");   // tile 6 done; tile 7 in flight
    } else {
      asm volatile("s_waitcnt vmcnt(0)" ::: "memory");   // tile 7 done
    }
    __builtin_amdgcn_s_barrier();

    f16x8 a[4];
#pragma unroll
    for (int of = 0; of < 4; ++of)
      a[of] = *(const f16x8*)(wp + (size_t)of * 16 * C + ci * 32);

#pragma unroll
    for (int nf = 0; nf < 4; ++nf) {
      int pxc = wpx + nf * 16 + fm;
      f16x8 bf;
#pragma unroll
      for (int j = 0; j < 8; ++j)
        bf[j] = (f16)buf[(kg * 8 + j) * 128 + pxc];   // 8x ds_read_b32, 4-way banked
#pragma unroll
      for (int of = 0; of < 4; ++of)
        acc[of][nf] = MFMA16(a[of], bf, acc[of][nf]);
    }
    __builtin_amdgcn_s_barrier();   // reads of buf done before its next DMA reuse
  }

#pragma unroll
  for (int of = 0; of < 4; ++of) {
    int orow = wo + of * 16 + kg * 4;
    f32x4 sh = *(const f32x4*)(shift + orow);
#pragma unroll
    for (int nf = 0; nf < 4; ++nf) {
      int n = n0 + wpx + nf * 16 + fm;
      f16x4 st;
#pragma unroll
      for (int r = 0; r < 4; ++r)
        st[r] = (f16)fmaxf(acc[of][nf][r] + sh[r], 0.0f);
      *(f16x4*)(out + ((size_t)b * P + n) * C + orow) = st;
    }
  }
}

// ---------------- direct-NCHW conv (R10 64-px version, kept for P=49) ----------------
template <int P>
__global__ __launch_bounds__(256) void conv_nchw(
    const float* __restrict__ X, const f16* __restrict__ W,
    const float* __restrict__ shift, f16* __restrict__ out) {
  const int C = 256;
  int n0 = blockIdx.x * 64;
  int t = threadIdx.x;
  int lane = t & 63, wave = t >> 6;
  int fm = lane & 15, kg = lane >> 4;

  __shared__ f16 Bs[2][64 * 40];

  int b0 = n0 / P, bp0 = n0 - b0 * P;
  bool safe = (bp0 + 64 <= P);

  int px = (t & 15) * 4;
  int cpr = (t >> 4) * 2;
  const float* xb = X + ((size_t)b0 * C) * P + bp0 + px;

  int ub[4], up[4];
  if (!safe) {
#pragma unroll
    for (int e = 0; e < 4; ++e) {
      int gn = n0 + px + e;
      ub[e] = gn / P;
      up[e] = gn - ub[e] * P;
    }
  }

  int wrow[4];
#pragma unroll
  for (int e = 0; e < 4; ++e) wrow[e] = pi_row(t & 15, e);
  int rrow[4];
#pragma unroll
  for (int nf = 0; nf < 4; ++nf) rrow[nf] = pi_row(nf * 4 + (fm >> 2), fm & 3);

  const f16* wp = W + (size_t)(wave * 64 + fm) * C + kg * 8;

  f32x4 rb[3][2];
#pragma unroll
  for (int s = 0; s < 3; ++s) {
    int cl = s * 32 + cpr;
    if (safe) {
      rb[s][0] = *(const f32x4*)(xb + (size_t)cl * P);
      rb[s][1] = *(const f32x4*)(xb + (size_t)(cl + 1) * P);
    } else {
#pragma unroll
      for (int e = 0; e < 4; ++e) {
        rb[s][0][e] = X[((size_t)ub[e] * C + cl) * P + up[e]];
        rb[s][1][e] = X[((size_t)ub[e] * C + cl + 1) * P + up[e]];
      }
    }
  }

  f32x4 acc[4][4] = {};
#pragma unroll
  for (int ci = 0; ci < 8; ++ci) {
    f16x8 a[4];
#pragma unroll
    for (int of = 0; of < 4; ++of)
      a[of] = *(const f16x8*)(wp + (size_t)of * 16 * C + ci * 32);

    f16* buf = Bs[ci & 1];
#pragma unroll
    for (int e = 0; e < 4; ++e) {
      f16x2 v;
      v[0] = (f16)rb[ci % 3][0][e];
      v[1] = (f16)rb[ci % 3][1][e];
      *(f16x2*)&buf[wrow[e] * 40 + cpr] = v;
    }
    if (ci + 3 < 8) {
      int cl = (ci + 3) * 32 + cpr;
      if (safe) {
        rb[ci % 3][0] = *(const f32x4*)(xb + (size_t)cl * P);
        rb[ci % 3][1] = *(const f32x4*)(xb + (size_t)(cl + 1) * P);
      } else {
#pragma unroll
        for (int e = 0; e < 4; ++e) {
          rb[ci % 3][0][e] = X[((size_t)ub[e] * C + cl) * P + up[e]];
          rb[ci % 3][1][e] = X[((size_t)ub[e] * C + cl + 1) * P + up[e]];
        }
      }
    }
    asm volatile("s_waitcnt lgkmcnt(0)" ::: "memory");
    __builtin_amdgcn_s_barrier();

    f16x8 b[4];
#pragma unroll
    for (int nf = 0; nf < 4; ++nf)
      b[nf] = *(const f16x8*)&buf[rrow[nf] * 40 + kg * 8];
#pragma unroll
    for (int of = 0; of < 4; ++of)
#pragma unroll
      for (int nf = 0; nf < 4; ++nf)
        acc[of][nf] = MFMA16(a[of], b[nf], acc[of][nf]);
  }

#pragma unroll
  for (int of = 0; of < 4; ++of) {
    int orow = wave * 64 + of * 16 + kg * 4;
    f32x4 sh = *(const f32x4*)(shift + orow);
#pragma unroll
    for (int nf = 0; nf < 4; ++nf) {
      int n = n0 + nf * 16 + fm;
      f16x4 st;
#pragma unroll
      for (int r = 0; r < 4; ++r)
        st[r] = (f16)fmaxf(acc[of][nf][r] + sh[r], 0.0f);
      *(f16x4*)(out + (size_t)n * C + orow) = st;
    }
  }
}

// ---------------- fused xcorr + head (R16 best-known) ----------------
__global__ __launch_bounds__(256) void xcorr_head(
    const f16* __restrict__ S /* [128][961][256] */,
    const f16* __restrict__ Kf /* [128][49][256] */,
    const f16* __restrict__ W1, const float* __restrict__ shift,
    const f16* __restrict__ W2p, const float* __restrict__ bias,
    float* __restrict__ out /* [128][20][625] */) {
  const int C = 256;
  int id = blockIdx.x;            // XCD-swizzled
  int x = id & 7;
  int r = id >> 3;
  int g = r % 7;
  int b = (r / 7) * 8 + x;

  int t = threadIdx.x;
  int w = t >> 6, lane = t & 63;
  int fm = lane & 15, kg = lane >> 4;
  int oi = g * 4 + w;             // 0..27

  __shared__ char F[100 * 512];   // 51200 B, row-XOR swizzle

  // ---- phase 1: xcorr ----
  if (oi < 25) {
    const f16* Sb = S + (size_t)b * 961 * 256 + lane * 4;
    const f16* Kb = Kf + (size_t)b * 49 * 256 + lane * 4;
    f16x4 acc[25] = {};
    for (int di = 0; di < 7; ++di) {
      const f16* sp = Sb + (size_t)(oi + di) * 31 * 256;
      f16x4 srow[31];
#pragma unroll
      for (int j = 0; j < 31; ++j) srow[j] = *(const f16x4*)(sp + (size_t)j * 256);
      const f16* kp = Kb + (size_t)di * 7 * 256;
      f16x4 krow[7];
#pragma unroll
      for (int j = 0; j < 7; ++j) krow[j] = *(const f16x4*)(kp + (size_t)j * 256);
#pragma unroll
      for (int dj = 0; dj < 7; ++dj) {
        f16x4 kv = krow[dj];
#pragma unroll
        for (int oj = 0; oj < 25; ++oj)
          acc[oj] += srow[oj + dj] * kv;
      }
    }
#pragma unroll
    for (int oj = 0; oj < 25; ++oj) {
      int n = w * 25 + oj;
      *(f16x4*)(F + ((n * 512 + lane * 8) ^ ((n & 7) << 4))) = acc[oj];
    }
  } else {
    f16x4 z = {};
#pragma unroll
    for (int oj = 0; oj < 25; ++oj) {
      int n = w * 25 + oj;
      *(f16x4*)(F + ((n * 512 + lane * 8) ^ ((n & 7) << 4))) = z;
    }
  }
  __syncthreads();

  // ---- phase 2: head conv1 (M=256, N=112 logical / 100 phys, K=256) ----
  const f16* wp = W1 + (size_t)(w * 64 + fm) * C + kg * 8;
  f32x4 acc1[4][7] = {};
  f16x8 a_cur[4], a_nxt[4];
#pragma unroll
  for (int of = 0; of < 4; ++of)
    a_cur[of] = *(const f16x8*)(wp + (size_t)of * 16 * C);
#pragma unroll
  for (int ci = 0; ci < 8; ++ci) {
    if (ci < 7) {
#pragma unroll
      for (int of = 0; of < 4; ++of)
        a_nxt[of] = *(const f16x8*)(wp + (size_t)of * 16 * C + (ci + 1) * 32);
    }
    f16x8 bf[7];
#pragma unroll
    for (int nf = 0; nf < 7; ++nf) {
      int n = nf * 16 + fm;
      int rn = n < 100 ? n : n - 100;
      bf[nf] = *(const f16x8*)(F + ((rn * 512 + (ci * 32 + kg * 8) * 2) ^ ((rn & 7) << 4)));
    }
    __builtin_amdgcn_s_setprio(1);
#pragma unroll
    for (int of = 0; of < 4; ++of)
#pragma unroll
      for (int nf = 0; nf < 7; ++nf)
        acc1[of][nf] = MFMA16(a_cur[of], bf[nf], acc1[of][nf]);
    __builtin_amdgcn_s_setprio(0);
#pragma unroll
    for (int of = 0; of < 4; ++of) a_cur[of] = a_nxt[of];
  }
  __syncthreads();

  // ReLU + shift -> f16 -> same LDS (skip n>=100)
#pragma unroll
  for (int of = 0; of < 4; ++of) {
    int orow = w * 64 + of * 16 + kg * 4;
    f32x4 sh = *(const f32x4*)(shift + orow);
#pragma unroll
    for (int nf = 0; nf < 7; ++nf) {
      int n = nf * 16 + fm;
      if (n < 100) {
        f16x4 st;
#pragma unroll
        for (int q = 0; q < 4; ++q)
          st[q] = (f16)fmaxf(acc1[of][nf][q] + sh[q], 0.0f);
        *(f16x4*)(F + ((n * 512 + orow * 2) ^ ((n & 7) << 4))) = st;
      }
    }
  }
  __syncthreads();

  // ---- phase 3: conv2 (M=32, 20 live; per-wave n-frags {w, w+4}) ----
  f32x4 acc2[2][2] = {};
  int nfa = w, nfb = w + 4;
  f16x8 w2_cur[2], w2_nxt[2];
  w2_cur[0] = *(const f16x8*)(W2p + (size_t)fm * C + kg * 8);
  w2_cur[1] = *(const f16x8*)(W2p + (size_t)(16 + fm) * C + kg * 8);
#pragma unroll
  for (int ci = 0; ci < 8; ++ci) {
    if (ci < 7) {
      w2_nxt[0] = *(const f16x8*)(W2p + (size_t)fm * C + (ci + 1) * 32 + kg * 8);
      w2_nxt[1] = *(const f16x8*)(W2p + (size_t)(16 + fm) * C + (ci + 1) * 32 + kg * 8);
    }
    int na = nfa * 16 + fm;
    f16x8 b0 = *(const f16x8*)(F + ((na * 512 + (ci * 32 + kg * 8) * 2) ^ ((na & 7) << 4)));
    __builtin_amdgcn_s_setprio(1);
    acc2[0][0] = MFMA16(w2_cur[0], b0, acc2[0][0]);
    acc2[1][0] = MFMA16(w2_cur[1], b0, acc2[1][0]);
    __builtin_amdgcn_s_setprio(0);
    if (nfb < 7) {
      int nb = nfb * 16 + fm;
      int rnb = nb < 100 ? nb : nb - 100;
      f16x8 b1 = *(const f16x8*)(F + ((rnb * 512 + (ci * 32 + kg * 8) * 2) ^ ((rnb & 7) << 4)));
      __builtin_amdgcn_s_setprio(1);
      acc2[0][1] = MFMA16(w2_cur[0], b1, acc2[0][1]);
      acc2[1][1] = MFMA16(w2_cur[1], b1, acc2[1][1]);
      __builtin_amdgcn_s_setprio(0);
    }
    w2_cur[0] = w2_nxt[0];
    w2_cur[1] = w2_nxt[1];
  }

#pragma unroll
  for (int q = 0; q < 2; ++q) {
    int nf = q ? nfb : nfa;
    if (nf >= 7) continue;
    int n = nf * 16 + fm;
    if (n < 100) {
      int oi2 = g * 4 + n / 25;
      int oj2 = n % 25;
      if (oi2 < 25) {
        float* op = out + (size_t)b * 12500 + oi2 * 25 + oj2;
#pragma unroll
        for (int of = 0; of < 2; ++of)
#pragma unroll
          for (int e = 0; e < 4; ++e) {
            int o = of * 16 + kg * 4 + e;
            if (o < 20) op[(size_t)o * 625] = acc2[of][q][e] + bias[o];
          }
      }
    }
  }
}

extern "C" void kernel_launch(void* const* d_in, const int* in_sizes, int n_in,
                              void* d_out, int out_size, void* d_ws, size_t ws_size,
                              hipStream_t stream) {
  const float* kernel_in = (const float*)d_in[0];
  const float* search    = (const float*)d_in[1];
  const float* w_k = (const float*)d_in[2];
  const float* g_k = (const float*)d_in[3];
  const float* b_k = (const float*)d_in[4];
  const float* m_k = (const float*)d_in[5];
  const float* v_k = (const float*)d_in[6];
  const float* w_s = (const float*)d_in[7];
  const float* g_s = (const float*)d_in[8];
  const float* b_s = (const float*)d_in[9];
  const float* m_s = (const float*)d_in[10];
  const float* v_s = (const float*)d_in[11];
  const float* w_h1 = (const float*)d_in[12];
  const float* g_h = (const float*)d_in[13];
  const float* b_h = (const float*)d_in[14];
  const float* m_h = (const float*)d_in[15];
  const float* v_h = (const float*)d_in[16];
  const float* w_h2 = (const float*)d_in[17];
  const float* bias_h2 = (const float*)d_in[18];
  float* out = (float*)d_out;

  char* ws = (char*)d_ws;
  f16* wk16  = (f16*)(ws + OFF_WK);
  f16* ws16  = (f16*)(ws + OFF_WS);
  f16* wh116 = (f16*)(ws + OFF_WH1);
  f16* w2p   = (f16*)(ws + OFF_W2P);
  float* shifts = (float*)(ws + OFF_SH);
  f16* sbuf = (f16*)(ws + OFF_S);
  f16* kbuf = (f16*)(ws + OFF_KF);

  prep_weights<<<256, 256, 0, stream>>>(w_k, g_k, b_k, m_k, v_k,
                                        w_s, g_s, b_s, m_s, v_s,
                                        w_h1, g_h, b_h, m_h, v_h, w_h2,
                                        wk16, ws16, wh116, w2p, shifts);

  // search branch: gload_lds, 3-buffer / 2-ahead counted-vmcnt pipeline
  conv_gl<<<dim3(1024), 512, 0, stream>>>(search, ws16, shifts + 256, sbuf);
  // kernel branch: 64-px blocks (R10 structure)
  conv_nchw<49><<<dim3(98), 256, 0, stream>>>(kernel_in, wk16, shifts + 0, kbuf);

  // fused depthwise-xcorr + head -> fp32 NCHW
  xcorr_head<<<dim3(896), 256, 0, stream>>>(
      sbuf, kbuf, wh116, shifts + 512, w2p, bias_h2, out);
}

// Round 22
// 160.291 us; speedup vs baseline: 1.0265x; 1.0265x over previous
//
#include <hip/hip_runtime.h>
#include <hip/hip_fp16.h>

typedef _Float16 f16;
typedef __attribute__((ext_vector_type(8))) _Float16 f16x8;
typedef __attribute__((ext_vector_type(4))) _Float16 f16x4;
typedef __attribute__((ext_vector_type(2))) _Float16 f16x2;
typedef __attribute__((ext_vector_type(4))) float f32x4;

#define MFMA16(a, b, c) __builtin_amdgcn_mfma_f32_16x16x32_f16((a), (b), (c), 0, 0, 0)

// direct global->LDS DMA, 16B per lane (dest = wave-uniform base + lane*16)
#define GL16(SRC, DST)                                                        \
  __builtin_amdgcn_global_load_lds(                                           \
      (const __attribute__((address_space(1))) unsigned int*)(SRC),           \
      (__attribute__((address_space(3))) unsigned int*)(DST), 16, 0, 0)

// ---------------- workspace layout (bytes) ----------------
#define OFF_WK   0u              // w_k folded f16 [256][256]
#define OFF_WS   131072u         // w_s folded f16 [256][256]
#define OFF_WH1  262144u         // w_h1 folded f16 [256][256]
#define OFF_W2P  393216u         // w_h2 padded f16 [32][256]
#define OFF_SH   409600u         // shifts f32 [3][256]
#define OFF_S    412672u         // s feat f16 [123008][256]
#define OFF_KF   63392768u       // k feat f16 [6272][256]

// ---------------- weight prep ----------------
__global__ __launch_bounds__(256) void prep_weights(
    const float* __restrict__ wk, const float* __restrict__ gk, const float* __restrict__ bk,
    const float* __restrict__ mk, const float* __restrict__ vk,
    const float* __restrict__ wsr, const float* __restrict__ gs, const float* __restrict__ bs,
    const float* __restrict__ ms, const float* __restrict__ vs,
    const float* __restrict__ wh1, const float* __restrict__ gh, const float* __restrict__ bh,
    const float* __restrict__ mh, const float* __restrict__ vh,
    const float* __restrict__ wh2,
    f16* __restrict__ wk16, f16* __restrict__ ws16, f16* __restrict__ wh116,
    f16* __restrict__ w2p, float* __restrict__ shifts) {
  int o = blockIdx.x;
  int t = threadIdx.x;
  float sck = gk[o] * rsqrtf(vk[o] + 1e-5f);
  float scs = gs[o] * rsqrtf(vs[o] + 1e-5f);
  float sch = gh[o] * rsqrtf(vh[o] + 1e-5f);
  int idx = o * 256 + t;
  wk16[idx]  = (f16)(wk[idx] * sck);
  ws16[idx]  = (f16)(wsr[idx] * scs);
  wh116[idx] = (f16)(wh1[idx] * sch);
  if (o < 32) w2p[idx] = (o < 20) ? (f16)wh2[idx] : (f16)0;
  if (t == 0) {
    shifts[o]       = bk[o] - mk[o] * sck;
    shifts[256 + o] = bs[o] - ms[o] * scs;
    shifts[512 + o] = bh[o] - mh[o] * sch;
  }
}

// π row permutation for LDS B-tile (conv49)
__device__ __forceinline__ int pi_row(int q, int r) {  // n = 4q + r (q in 0..15)
  return (q ^ (r << 2)) + (r << 4);
}

// ---------------- conv961 via global_load_lds + counted vmcnt (R20 best) ----------------
// Tile 128px x 256o, 8 waves. LDS: 2 x fp32 [32c][128px] LINEAR buffers (DMA dest).
// Per step: issue DMA for tile ci+1 -> vmcnt(2) (tile ci done; ci+1 stays in flight
// across the barrier) -> s_barrier -> b32-column frag reads + cvt -> 16 MFMA ->
// s_barrier (protect buf from tile ci+2 DMA). No staging VGPRs.
__global__ __launch_bounds__(512) void conv_gl(
    const float* __restrict__ X, const f16* __restrict__ W,
    const float* __restrict__ shift, f16* __restrict__ out) {
  const int C = 256, P = 961;
  int b = blockIdx.x >> 3;
  int ti = blockIdx.x & 7;
  int n0 = ti * 128; if (n0 > P - 128) n0 = P - 128;   // tail overlap: dup identical writes
  int t = threadIdx.x;
  int w = t >> 6, lane = t & 63;
  int fm = lane & 15, kg = lane >> 4;
  int wo = (w & 3) * 64;          // o-base (4 groups)
  int wpx = (w >> 2) * 64;        // px-half

  __shared__ float Bs[2][32 * 128];   // [buf][c][px] fp32, 16 KB each

  // staging: wave w owns rows 4w..4w+3; instr j covers rows {4w+2j, 4w+2j+1}
  // per-lane src: row 4w+2j+(lane>>5), px (lane&31)*4 (16B contiguous per lane)
  const float* s_src0 = X + ((size_t)b * C + 4 * w + (lane >> 5)) * P + n0 + (lane & 31) * 4;

  const f16* wp = W + (size_t)(wo + fm) * C + kg * 8;

  // prologue: tile 0 DMA
  GL16(s_src0,         &Bs[0][(4 * w) * 128]);
  GL16(s_src0 + 2 * P, &Bs[0][(4 * w + 2) * 128]);

  f32x4 acc[4][4] = {};
#pragma unroll
  for (int ci = 0; ci < 8; ++ci) {
    float* buf = Bs[ci & 1];
    if (ci < 7) {
      const float* s = s_src0 + (size_t)(ci + 1) * 32 * P;
      float* d = Bs[(ci + 1) & 1];
      GL16(s,         &d[(4 * w) * 128]);
      GL16(s + 2 * P, &d[(4 * w + 2) * 128]);
      asm volatile("s_waitcnt vmcnt(2)" ::: "memory");   // tile ci complete; ci+1 in flight
    } else {
      asm volatile("s_waitcnt vmcnt(0)" ::: "memory");
    }
    __builtin_amdgcn_s_barrier();

    f16x8 a[4];
#pragma unroll
    for (int of = 0; of < 4; ++of)
      a[of] = *(const f16x8*)(wp + (size_t)of * 16 * C + ci * 32);

#pragma unroll
    for (int nf = 0; nf < 4; ++nf) {
      int pxc = wpx + nf * 16 + fm;
      f16x8 bf;
#pragma unroll
      for (int j = 0; j < 8; ++j)
        bf[j] = (f16)buf[(kg * 8 + j) * 128 + pxc];   // 8x ds_read_b32, 4-way banked
#pragma unroll
      for (int of = 0; of < 4; ++of)
        acc[of][nf] = MFMA16(a[of], bf, acc[of][nf]);
    }
    __builtin_amdgcn_s_barrier();   // all reads of buf done before tile ci+2 DMA
  }

#pragma unroll
  for (int of = 0; of < 4; ++of) {
    int orow = wo + of * 16 + kg * 4;
    f32x4 sh = *(const f32x4*)(shift + orow);
#pragma unroll
    for (int nf = 0; nf < 4; ++nf) {
      int n = n0 + wpx + nf * 16 + fm;
      f16x4 st;
#pragma unroll
      for (int r = 0; r < 4; ++r)
        st[r] = (f16)fmaxf(acc[of][nf][r] + sh[r], 0.0f);
      *(f16x4*)(out + ((size_t)b * P + n) * C + orow) = st;
    }
  }
}

// ---------------- direct-NCHW conv (R10 64-px version, kept for P=49) ----------------
template <int P>
__global__ __launch_bounds__(256) void conv_nchw(
    const float* __restrict__ X, const f16* __restrict__ W,
    const float* __restrict__ shift, f16* __restrict__ out) {
  const int C = 256;
  int n0 = blockIdx.x * 64;
  int t = threadIdx.x;
  int lane = t & 63, wave = t >> 6;
  int fm = lane & 15, kg = lane >> 4;

  __shared__ f16 Bs[2][64 * 40];

  int b0 = n0 / P, bp0 = n0 - b0 * P;
  bool safe = (bp0 + 64 <= P);

  int px = (t & 15) * 4;
  int cpr = (t >> 4) * 2;
  const float* xb = X + ((size_t)b0 * C) * P + bp0 + px;

  int ub[4], up[4];
  if (!safe) {
#pragma unroll
    for (int e = 0; e < 4; ++e) {
      int gn = n0 + px + e;
      ub[e] = gn / P;
      up[e] = gn - ub[e] * P;
    }
  }

  int wrow[4];
#pragma unroll
  for (int e = 0; e < 4; ++e) wrow[e] = pi_row(t & 15, e);
  int rrow[4];
#pragma unroll
  for (int nf = 0; nf < 4; ++nf) rrow[nf] = pi_row(nf * 4 + (fm >> 2), fm & 3);

  const f16* wp = W + (size_t)(wave * 64 + fm) * C + kg * 8;

  f32x4 rb[3][2];
#pragma unroll
  for (int s = 0; s < 3; ++s) {
    int cl = s * 32 + cpr;
    if (safe) {
      rb[s][0] = *(const f32x4*)(xb + (size_t)cl * P);
      rb[s][1] = *(const f32x4*)(xb + (size_t)(cl + 1) * P);
    } else {
#pragma unroll
      for (int e = 0; e < 4; ++e) {
        rb[s][0][e] = X[((size_t)ub[e] * C + cl) * P + up[e]];
        rb[s][1][e] = X[((size_t)ub[e] * C + cl + 1) * P + up[e]];
      }
    }
  }

  f32x4 acc[4][4] = {};
#pragma unroll
  for (int ci = 0; ci < 8; ++ci) {
    f16x8 a[4];
#pragma unroll
    for (int of = 0; of < 4; ++of)
      a[of] = *(const f16x8*)(wp + (size_t)of * 16 * C + ci * 32);

    f16* buf = Bs[ci & 1];
#pragma unroll
    for (int e = 0; e < 4; ++e) {
      f16x2 v;
      v[0] = (f16)rb[ci % 3][0][e];
      v[1] = (f16)rb[ci % 3][1][e];
      *(f16x2*)&buf[wrow[e] * 40 + cpr] = v;
    }
    if (ci + 3 < 8) {
      int cl = (ci + 3) * 32 + cpr;
      if (safe) {
        rb[ci % 3][0] = *(const f32x4*)(xb + (size_t)cl * P);
        rb[ci % 3][1] = *(const f32x4*)(xb + (size_t)(cl + 1) * P);
      } else {
#pragma unroll
        for (int e = 0; e < 4; ++e) {
          rb[ci % 3][0][e] = X[((size_t)ub[e] * C + cl) * P + up[e]];
          rb[ci % 3][1][e] = X[((size_t)ub[e] * C + cl + 1) * P + up[e]];
        }
      }
    }
    asm volatile("s_waitcnt lgkmcnt(0)" ::: "memory");
    __builtin_amdgcn_s_barrier();

    f16x8 b[4];
#pragma unroll
    for (int nf = 0; nf < 4; ++nf)
      b[nf] = *(const f16x8*)&buf[rrow[nf] * 40 + kg * 8];
#pragma unroll
    for (int of = 0; of < 4; ++of)
#pragma unroll
      for (int nf = 0; nf < 4; ++nf)
        acc[of][nf] = MFMA16(a[of], b[nf], acc[of][nf]);
  }

#pragma unroll
  for (int of = 0; of < 4; ++of) {
    int orow = wave * 64 + of * 16 + kg * 4;
    f32x4 sh = *(const f32x4*)(shift + orow);
#pragma unroll
    for (int nf = 0; nf < 4; ++nf) {
      int n = n0 + nf * 16 + fm;
      f16x4 st;
#pragma unroll
      for (int r = 0; r < 4; ++r)
        st[r] = (f16)fmaxf(acc[of][nf][r] + sh[r], 0.0f);
      *(f16x4*)(out + (size_t)n * C + orow) = st;
    }
  }
}

// ---------------- fused xcorr + head (R16 best-known) ----------------
__global__ __launch_bounds__(256) void xcorr_head(
    const f16* __restrict__ S /* [128][961][256] */,
    const f16* __restrict__ Kf /* [128][49][256] */,
    const f16* __restrict__ W1, const float* __restrict__ shift,
    const f16* __restrict__ W2p, const float* __restrict__ bias,
    float* __restrict__ out /* [128][20][625] */) {
  const int C = 256;
  int id = blockIdx.x;            // XCD-swizzled
  int x = id & 7;
  int r = id >> 3;
  int g = r % 7;
  int b = (r / 7) * 8 + x;

  int t = threadIdx.x;
  int w = t >> 6, lane = t & 63;
  int fm = lane & 15, kg = lane >> 4;
  int oi = g * 4 + w;             // 0..27

  __shared__ char F[100 * 512];   // 51200 B, row-XOR swizzle

  // ---- phase 1: xcorr ----
  if (oi < 25) {
    const f16* Sb = S + (size_t)b * 961 * 256 + lane * 4;
    const f16* Kb = Kf + (size_t)b * 49 * 256 + lane * 4;
    f16x4 acc[25] = {};
    for (int di = 0; di < 7; ++di) {
      const f16* sp = Sb + (size_t)(oi + di) * 31 * 256;
      f16x4 srow[31];
#pragma unroll
      for (int j = 0; j < 31; ++j) srow[j] = *(const f16x4*)(sp + (size_t)j * 256);
      const f16* kp = Kb + (size_t)di * 7 * 256;
      f16x4 krow[7];
#pragma unroll
      for (int j = 0; j < 7; ++j) krow[j] = *(const f16x4*)(kp + (size_t)j * 256);
#pragma unroll
      for (int dj = 0; dj < 7; ++dj) {
        f16x4 kv = krow[dj];
#pragma unroll
        for (int oj = 0; oj < 25; ++oj)
          acc[oj] += srow[oj + dj] * kv;
      }
    }
#pragma unroll
    for (int oj = 0; oj < 25; ++oj) {
      int n = w * 25 + oj;
      *(f16x4*)(F + ((n * 512 + lane * 8) ^ ((n & 7) << 4))) = acc[oj];
    }
  } else {
    f16x4 z = {};
#pragma unroll
    for (int oj = 0; oj < 25; ++oj) {
      int n = w * 25 + oj;
      *(f16x4*)(F + ((n * 512 + lane * 8) ^ ((n & 7) << 4))) = z;
    }
  }
  __syncthreads();

  // ---- phase 2: head conv1 (M=256, N=112 logical / 100 phys, K=256) ----
  const f16* wp = W1 + (size_t)(w * 64 + fm) * C + kg * 8;
  f32x4 acc1[4][7] = {};
  f16x8 a_cur[4], a_nxt[4];
#pragma unroll
  for (int of = 0; of < 4; ++of)
    a_cur[of] = *(const f16x8*)(wp + (size_t)of * 16 * C);
#pragma unroll
  for (int ci = 0; ci < 8; ++ci) {
    if (ci < 7) {
#pragma unroll
      for (int of = 0; of < 4; ++of)
        a_nxt[of] = *(const f16x8*)(wp + (size_t)of * 16 * C + (ci + 1) * 32);
    }
    f16x8 bf[7];
#pragma unroll
    for (int nf = 0; nf < 7; ++nf) {
      int n = nf * 16 + fm;
      int rn = n < 100 ? n : n - 100;
      bf[nf] = *(const f16x8*)(F + ((rn * 512 + (ci * 32 + kg * 8) * 2) ^ ((rn & 7) << 4)));
    }
    __builtin_amdgcn_s_setprio(1);
#pragma unroll
    for (int of = 0; of < 4; ++of)
#pragma unroll
      for (int nf = 0; nf < 7; ++nf)
        acc1[of][nf] = MFMA16(a_cur[of], bf[nf], acc1[of][nf]);
    __builtin_amdgcn_s_setprio(0);
#pragma unroll
    for (int of = 0; of < 4; ++of) a_cur[of] = a_nxt[of];
  }
  __syncthreads();

  // ReLU + shift -> f16 -> same LDS (skip n>=100)
#pragma unroll
  for (int of = 0; of < 4; ++of) {
    int orow = w * 64 + of * 16 + kg * 4;
    f32x4 sh = *(const f32x4*)(shift + orow);
#pragma unroll
    for (int nf = 0; nf < 7; ++nf) {
      int n = nf * 16 + fm;
      if (n < 100) {
        f16x4 st;
#pragma unroll
        for (int q = 0; q < 4; ++q)
          st[q] = (f16)fmaxf(acc1[of][nf][q] + sh[q], 0.0f);
        *(f16x4*)(F + ((n * 512 + orow * 2) ^ ((n & 7) << 4))) = st;
      }
    }
  }
  __syncthreads();

  // ---- phase 3: conv2 (M=32, 20 live; per-wave n-frags {w, w+4}) ----
  f32x4 acc2[2][2] = {};
  int nfa = w, nfb = w + 4;
  f16x8 w2_cur[2], w2_nxt[2];
  w2_cur[0] = *(const f16x8*)(W2p + (size_t)fm * C + kg * 8);
  w2_cur[1] = *(const f16x8*)(W2p + (size_t)(16 + fm) * C + kg * 8);
#pragma unroll
  for (int ci = 0; ci < 8; ++ci) {
    if (ci < 7) {
      w2_nxt[0] = *(const f16x8*)(W2p + (size_t)fm * C + (ci + 1) * 32 + kg * 8);
      w2_nxt[1] = *(const f16x8*)(W2p + (size_t)(16 + fm) * C + (ci + 1) * 32 + kg * 8);
    }
    int na = nfa * 16 + fm;
    f16x8 b0 = *(const f16x8*)(F + ((na * 512 + (ci * 32 + kg * 8) * 2) ^ ((na & 7) << 4)));
    __builtin_amdgcn_s_setprio(1);
    acc2[0][0] = MFMA16(w2_cur[0], b0, acc2[0][0]);
    acc2[1][0] = MFMA16(w2_cur[1], b0, acc2[1][0]);
    __builtin_amdgcn_s_setprio(0);
    if (nfb < 7) {
      int nb = nfb * 16 + fm;
      int rnb = nb < 100 ? nb : nb - 100;
      f16x8 b1 = *(const f16x8*)(F + ((rnb * 512 + (ci * 32 + kg * 8) * 2) ^ ((rnb & 7) << 4)));
      __builtin_amdgcn_s_setprio(1);
      acc2[0][1] = MFMA16(w2_cur[0], b1, acc2[0][1]);
      acc2[1][1] = MFMA16(w2_cur[1], b1, acc2[1][1]);
      __builtin_amdgcn_s_setprio(0);
    }
    w2_cur[0] = w2_nxt[0];
    w2_cur[1] = w2_nxt[1];
  }

#pragma unroll
  for (int q = 0; q < 2; ++q) {
    int nf = q ? nfb : nfa;
    if (nf >= 7) continue;
    int n = nf * 16 + fm;
    if (n < 100) {
      int oi2 = g * 4 + n / 25;
      int oj2 = n % 25;
      if (oi2 < 25) {
        float* op = out + (size_t)b * 12500 + oi2 * 25 + oj2;
#pragma unroll
        for (int of = 0; of < 2; ++of)
#pragma unroll
          for (int e = 0; e < 4; ++e) {
            int o = of * 16 + kg * 4 + e;
            if (o < 20) op[(size_t)o * 625] = acc2[of][q][e] + bias[o];
          }
      }
    }
  }
}

extern "C" void kernel_launch(void* const* d_in, const int* in_sizes, int n_in,
                              void* d_out, int out_size, void* d_ws, size_t ws_size,
                              hipStream_t stream) {
  const float* kernel_in = (const float*)d_in[0];
  const float* search    = (const float*)d_in[1];
  const float* w_k = (const float*)d_in[2];
  const float* g_k = (const float*)d_in[3];
  const float* b_k = (const float*)d_in[4];
  const float* m_k = (const float*)d_in[5];
  const float* v_k = (const float*)d_in[6];
  const float* w_s = (const float*)d_in[7];
  const float* g_s = (const float*)d_in[8];
  const float* b_s = (const float*)d_in[9];
  const float* m_s = (const float*)d_in[10];
  const float* v_s = (const float*)d_in[11];
  const float* w_h1 = (const float*)d_in[12];
  const float* g_h = (const float*)d_in[13];
  const float* b_h = (const float*)d_in[14];
  const float* m_h = (const float*)d_in[15];
  const float* v_h = (const float*)d_in[16];
  const float* w_h2 = (const float*)d_in[17];
  const float* bias_h2 = (const float*)d_in[18];
  float* out = (float*)d_out;

  char* ws = (char*)d_ws;
  f16* wk16  = (f16*)(ws + OFF_WK);
  f16* ws16  = (f16*)(ws + OFF_WS);
  f16* wh116 = (f16*)(ws + OFF_WH1);
  f16* w2p   = (f16*)(ws + OFF_W2P);
  float* shifts = (float*)(ws + OFF_SH);
  f16* sbuf = (f16*)(ws + OFF_S);
  f16* kbuf = (f16*)(ws + OFF_KF);

  prep_weights<<<256, 256, 0, stream>>>(w_k, g_k, b_k, m_k, v_k,
                                        w_s, g_s, b_s, m_s, v_s,
                                        w_h1, g_h, b_h, m_h, v_h, w_h2,
                                        wk16, ws16, wh116, w2p, shifts);

  // search branch: global_load_lds + counted-vmcnt pipeline (R20 best: 2-buffer/1-ahead)
  conv_gl<<<dim3(1024), 512, 0, stream>>>(search, ws16, shifts + 256, sbuf);
  // kernel branch: 64-px blocks (R10 structure)
  conv_nchw<49><<<dim3(98), 256, 0, stream>>>(kernel_in, wk16, shifts + 0, kbuf);

  // fused depthwise-xcorr + head -> fp32 NCHW
  xcorr_head<<<dim3(896), 256, 0, stream>>>(
      sbuf, kbuf, wh116, shifts + 512, w2p, bias_h2, out);
}